// Round 9
// baseline (223.244 us; speedup 1.0000x reference)
//
#include <hip/hip_runtime.h>

typedef unsigned short u16;
typedef unsigned int   u32;
typedef __attribute__((ext_vector_type(4))) float f32x4;
typedef __attribute__((ext_vector_type(8))) short bf16x8;
typedef __attribute__((ext_vector_type(4))) unsigned short u16x4;
typedef __attribute__((ext_vector_type(8))) unsigned short u16x8;

__device__ __forceinline__ u16 f2bf(float f) {
  union { float f; u32 u; } v; v.f = f;
  u32 r = v.u + 0x7FFFu + ((v.u >> 16) & 1u);   // round-to-nearest-even
  return (u16)(r >> 16);
}

__device__ __forceinline__ float bcast(float v, int l) {
  return __uint_as_float(__builtin_amdgcn_readlane(__float_as_uint(v), l));
}

// ---------------- Kernel 1: Cayley Q = 2*(I+S)^-1 - I, S = 0.5(R - R^T) ----
__global__ __launch_bounds__(256, 1) void cayley_kernel(
    const float* __restrict__ R, float* __restrict__ Q) {
  const int b  = blockIdx.x;
  const int t  = threadIdx.x;
  const int j  = t & 63;                // column owner (lane)
  const int iw = t >> 6;                // wave = row-block owner
  __shared__ float Rl[64][65];          // staged R (padded: transpose-read free)
  __shared__ float prow[2][2][64];      // [k parity][A|B][j]
  const float* Rb = R + (size_t)b * 4096;
  for (int idx = t; idx < 4096; idx += 256)
    Rl[idx >> 6][idx & 63] = Rb[idx];
  __syncthreads();
  float Ac[16], Bc[16];                 // A[16iw+i'][j], B[16iw+i'][j]
  #pragma unroll
  for (int i2 = 0; i2 < 16; ++i2) {
    const int i = iw*16 + i2;
    float s = 0.5f * (Rl[i][j] - Rl[j][i]);
    Ac[i2] = (i == j) ? (1.0f + s) : s;
    Bc[i2] = (i == j) ? 1.0f : 0.0f;
  }
  __syncthreads();
  #pragma unroll
  for (int kb = 0; kb < 4; ++kb) {
    #pragma unroll
    for (int kp = 0; kp < 16; ++kp) {
      const int k = kb*16 + kp;         // compile-time constant
      if (iw == kb) {                   // wave-uniform: pivot wave scales row k
        float pinv = 1.0f / bcast(Ac[kp], k);
        float ar = Ac[kp] * pinv;
        float br = Bc[kp] * pinv;
        Ac[kp] = ar; Bc[kp] = br;
        prow[k & 1][0][j] = ar;
        prow[k & 1][1][j] = br;
      }
      __syncthreads();
      const float ar = prow[k & 1][0][j];
      const float br = prow[k & 1][1][j];
      #pragma unroll
      for (int i2 = 0; i2 < 16; ++i2) { // eliminate own rows (static idx)
        float f = bcast(Ac[i2], k);     // A[16iw+i2][k], pre-update (lockstep)
        if (iw == kb && i2 == kp) f = 0.0f;   // pivot row preserved
        Ac[i2] -= f * ar;
        Bc[i2] -= f * br;
      }
    }
  }
  float* Qb = Q + (size_t)b * 4096;
  #pragma unroll
  for (int i2 = 0; i2 < 16; ++i2) {
    const int i = iw*16 + i2;
    Qb[i*64 + j] = 2.0f * Bc[i2] - ((i == j) ? 1.0f : 0.0f);
  }
}

// ---------------- Kernel 2: rot superblocks -> bf16 ------------------------
__global__ __launch_bounds__(256) void rotbuild_kernel(
    const float* __restrict__ Q, u16* __restrict__ rotb) {
  const int s = blockIdx.x;
  const int t = threadIdx.x;
  __shared__ float Q1l[2][64][65];      // padded
  __shared__ f32x4 Q0l[2][64][16];      // [dh][k][c4]
  const float* Q0g = Q + (size_t)(2*s) * 4096;        // factor 0: blocks 2s,2s+1
  const float* Q1g = Q + (size_t)(64 + 2*s) * 4096;   // factor 1 starts at block 64
  for (int i = t; i < 2*4096; i += 256) {
    int e = i >> 12, r = (i >> 6) & 63, c = i & 63;
    Q1l[e][r][c] = Q1g[i];
    ((float*)&Q0l[e][r][0])[c] = Q0g[i];
  }
  __syncthreads();
  const int a_l = t & 127;
  const int dh  = t >> 7;               // c-half this thread fills
  const int g   = a_l >> 5;             // local butterfly perm (involution)
  const int pa  = a_l + ((g == 1) ? 32 : (g == 2) ? -32 : 0);
  const int e = pa >> 6, pa64 = pa & 63;
  float q1v[32];
  #pragma unroll
  for (int jj = 0; jj < 32; ++jj) q1v[jj] = Q1l[e][pa64][dh*32 + jj];
  f32x4 acc4[16] = {};
  #pragma unroll
  for (int jj = 0; jj < 32; ++jj) {
    #pragma unroll
    for (int c4 = 0; c4 < 16; ++c4)
      acc4[c4] += q1v[jj] * Q0l[dh][e*32 + jj][c4];   // broadcast LDS read
  }
  u16* dst = rotb + (size_t)s*16384 + (size_t)a_l*128 + dh*64;
  #pragma unroll
  for (int c4 = 0; c4 < 16; ++c4) {
    u16x4 o;
    o.x = f2bf(acc4[c4].x); o.y = f2bf(acc4[c4].y);
    o.z = f2bf(acc4[c4].z); o.w = f2bf(acc4[c4].w);
    *(u16x4*)&dst[c4*4] = o;
  }
}

// ---------------- Kernel 3: SW = (W @ rot^T) * s -> bf16, MFMA -------------
__global__ __launch_bounds__(256) void wtrans_kernel(
    const float* __restrict__ W, const u16* __restrict__ rotb,
    const float* __restrict__ sscale, u16* __restrict__ SW) {
  const int rt = blockIdx.x;            // row tile 0..31
  const int s  = blockIdx.y;            // superblock 0..31
  const int t  = threadIdx.x;
  __shared__ u16 Asw[128*128];          // W tile bf16, swizzled
  __shared__ u16 Bsw[128*128];          // rot_s bf16, swizzled
  // stage A: granule g: row=g>>5, gc=g&31 (f32x4). Coalesced 16B/lane.
  #pragma unroll
  for (int p = 0; p < 16; ++p) {
    const int g = p*256 + t;
    const int row = g >> 5, gc = g & 31;
    float4 v = *(const float4*)(W + (size_t)(rt*128 + row)*4096 + s*128 + gc*4);
    u16x4 o;
    o.x = f2bf(v.x); o.y = f2bf(v.y); o.z = f2bf(v.z); o.w = f2bf(v.w);
    const int chunk = (gc >> 1) ^ (row & 7);
    *(u16x4*)&Asw[row*128 + chunk*8 + (gc & 1)*4] = o;
  }
  // stage B: granule g: row=g>>4, ch=g&15 (u16x8). Coalesced 16B/lane.
  const u16* rsrc = rotb + (size_t)s*16384;
  #pragma unroll
  for (int p = 0; p < 8; ++p) {
    const int g = p*256 + t;
    const int row = g >> 4, ch = g & 15;
    u16x8 v = *(const u16x8*)(rsrc + row*128 + ch*8);
    *(u16x8*)&Bsw[row*128 + ((ch ^ (row & 7))*8)] = v;
  }
  __syncthreads();
  const int w = t >> 6, l = t & 63;
  const int fr = l & 15, fq = l >> 4;
  const int wm = (w >> 1)*64, wn = (w & 1)*64;
  f32x4 acc[4][4] = {};
  #pragma unroll
  for (int ks = 0; ks < 4; ++ks) {
    bf16x8 af[4], bfr[4];
    #pragma unroll
    for (int m = 0; m < 4; ++m)
      af[m] = *(const bf16x8*)&Asw[(wm + m*16 + fr)*128 + (((ks*4 + fq) ^ (fr & 7))*8)];
    #pragma unroll
    for (int n = 0; n < 4; ++n)
      bfr[n] = *(const bf16x8*)&Bsw[(wn + n*16 + fr)*128 + (((ks*4 + fq) ^ (fr & 7))*8)];
    #pragma unroll
    for (int m = 0; m < 4; ++m)
      #pragma unroll
      for (int n = 0; n < 4; ++n)
        acc[m][n] = __builtin_amdgcn_mfma_f32_16x16x32_bf16(
            af[m], bfr[n], acc[m][n], 0, 0, 0);
  }
  // epilogue: C/D col = fr (output col), row = fq*4 + reg; scale by boft_s
  #pragma unroll
  for (int m = 0; m < 4; ++m) {
    #pragma unroll
    for (int r = 0; r < 4; ++r) {
      const int row = rt*128 + wm + m*16 + fq*4 + r;
      const float sc = sscale[row];
      #pragma unroll
      for (int n = 0; n < 4; ++n) {
        const int col = s*128 + wn + n*16 + fr;
        SW[(size_t)row*4096 + col] = f2bf(acc[m][n][r] * sc);
      }
    }
  }
}

// ---------------- Kernel 4: x f32 -> bf16 ----------------------------------
__global__ __launch_bounds__(256) void cvt_kernel(
    const float* __restrict__ x, u16* __restrict__ xb) {
  const size_t i = (size_t)blockIdx.x * 256 + threadIdx.x;  // 8 elems/thread
  const float4* p = (const float4*)x + i*2;
  float4 a = p[0], b = p[1];
  u16x8 o;
  o[0] = f2bf(a.x); o[1] = f2bf(a.y); o[2] = f2bf(a.z); o[3] = f2bf(a.w);
  o[4] = f2bf(b.x); o[5] = f2bf(b.y); o[6] = f2bf(b.z); o[7] = f2bf(b.w);
  *(u16x8*)(xb + i*8) = o;
}

// ---------------- Kernel 5: bf16 MFMA GEMM — 256^2 8-phase, pipelined ------
// R8->R9: ds_read/MFMA were serialized per phase (MfmaUtil 38.8%). Now frag
// reads issue ONE PHASE AHEAD: P0 reads A-half0 + ALL B, P1 reads A-half1
// into a second reg set (aP/aQ ping-pong). Compiler emits counted lgkmcnt
// from real deps: MFMA(0,0) waits lgkmcnt(4) (B1 in flight), MFMA(0,1) waits
// lgkmcnt(8) (A1 in flight) -> LDS reads drain under MFMA. Cross-wave safety:
// each wave's B-reads lgkm-complete before its P1-MFMA, hence before any
// wave's P2 stgB(cur). Counted vmcnt ledger unchanged. Conflicts = 0 (R7).
#define GLDS16(g, l)                                                   \
  __builtin_amdgcn_global_load_lds(                                    \
      (const __attribute__((address_space(1))) void*)(g),              \
      (__attribute__((address_space(3))) void*)(l), 16, 0, 0)

__device__ __forceinline__ void bar() {
  asm volatile("" ::: "memory");
  __builtin_amdgcn_s_barrier();
  asm volatile("" ::: "memory");
}

__global__ __launch_bounds__(512, 2) void gemm_kernel(
    const u16* __restrict__ A, const u16* __restrict__ B,
    const float* __restrict__ bias, float* __restrict__ C) {
  constexpr int K = 4096, N = 4096, NT = 64;   // K-tiles of BK=64
  __shared__ u16 As[2*256*64];                 // [buf][256 rows][64 cols]
  __shared__ u16 Bs[2*256*64];
  const int t = threadIdx.x;
  const int w = t >> 6, l = t & 63;
  const int wr = w >> 2, wc = w & 3;            // wave -> (2 x 4) grid
  const int fr = l & 15, fq = l >> 4;

  // XCD-aware swizzle (nwg=256, %8==0 -> simple bijective form)
  const int wg  = blockIdx.x;
  const int swz = (wg & 7) * 32 + (wg >> 3);
  const int m0  = (swz & 15) * 256, n0 = (swz >> 4) * 256;

  // staging: thread t fills LDS-linear granule (row = w*8 + (l>>3), c = l&7);
  // that slot must hold logical col (l&7) ^ (row&7)  [row&7 = (l>>3)&7].
  const int grow = w*8 + (l >> 3);                       // + o*64 + half*128
  const int gcol = ((l & 7) ^ ((l >> 3) & 7)) * 8;
  const u16* aS = A + (size_t)(m0 + grow) * K + gcol;
  const u16* bS = B + (size_t)(n0 + grow) * K + gcol;
  const int wLds = w * 512;                               // u16, wave-uniform

  // read: logical col = fq + 4*ks; stored col = (fq ^ (fr&7)) ^ 4*ks
  const int colbase = (fq ^ (fr & 7)) * 8;                // u16; ks flips ^32
  const u16* aRd = As + (wr*128 + fr)*64;  // + cur*16384 + mf*1024 + (colbase^(ks<<5))
  const u16* bRd = Bs + (wc*64  + fr)*64;

  auto stgA = [&](int buf, int half, int o, int kt_) {
    GLDS16(aS + (size_t)(half*128 + o*64) * K + (size_t)kt_*64,
           As + buf*16384 + half*8192 + o*4096 + wLds);
  };
  auto stgB = [&](int buf, int half, int o, int kt_) {
    GLDS16(bS + (size_t)(half*128 + o*64) * K + (size_t)kt_*64,
           Bs + buf*16384 + half*8192 + o*4096 + wLds);
  };

  f32x4 acc[8][4] = {};
  bf16x8 aP[4][2], aQ[4][2], bFr[4][2];        // ping/pong A, full-tile B

  // prologue: B(0)->buf0, A(0)->buf0, B(1)->buf1  (order matters for vmcnt)
  stgB(0,0,0,0); stgB(0,0,1,0); stgB(0,1,0,0); stgB(0,1,1,0);
  stgA(0,0,0,0); stgA(0,0,1,0); stgA(0,1,0,0); stgA(0,1,1,0);
  stgB(1,0,0,1); stgB(1,0,1,1); stgB(1,1,0,1); stgB(1,1,1,1);
  asm volatile("s_waitcnt vmcnt(4)" ::: "memory");   // tile0 landed, B(1) in flight
  bar();

  for (int kt = 0; kt < NT; ++kt) {
    const int cur = kt & 1;
    const u16* aC = aRd + cur*16384;
    const u16* bC = bRd + cur*16384;
    auto lda = [&](bf16x8 (&dst)[4][2], int mh) {
      #pragma unroll
      for (int m = 0; m < 4; ++m)
        #pragma unroll
        for (int ks = 0; ks < 2; ++ks)
          dst[m][ks] = *(const bf16x8*)(aC + (mh*4 + m)*1024 + (colbase ^ (ks << 5)));
    };
    auto ldbAll = [&]() {
      #pragma unroll
      for (int n = 0; n < 4; ++n)
        #pragma unroll
        for (int ks = 0; ks < 2; ++ks)
          bFr[n][ks] = *(const bf16x8*)(bC + n*1024 + (colbase ^ (ks << 5)));
    };
    auto mma = [&](bf16x8 (&af)[4][2], int mh, int nh) {
      __builtin_amdgcn_s_setprio(1);
      #pragma unroll
      for (int m = 0; m < 4; ++m)
        #pragma unroll
        for (int n = 0; n < 2; ++n)
          #pragma unroll
          for (int ks = 0; ks < 2; ++ks)
            acc[mh*4 + m][nh*2 + n] = __builtin_amdgcn_mfma_f32_16x16x32_bf16(
                af[m][ks], bFr[nh*2 + n][ks], acc[mh*4 + m][nh*2 + n], 0, 0, 0);
      __builtin_amdgcn_s_setprio(0);
    };
    // ---- P0: stage A(kt+1)h0 ; read A0 + ALL B ----
    if (kt + 1 < NT) { stgA(cur^1, 0, 0, kt+1); stgA(cur^1, 0, 1, kt+1); }
    lda(aP, 0);
    ldbAll();
    bar();
    mma(aP, 0, 0);          // waits A0+B0 (lgkmcnt 4: B1 drains under MFMA)
    bar();
    // ---- P1: stage A(kt+1)h1 ; read A1 (pong) ----
    if (kt + 1 < NT) { stgA(cur^1, 1, 0, kt+1); stgA(cur^1, 1, 1, kt+1); }
    lda(aQ, 1);
    bar();
    mma(aP, 0, 1);          // waits B1 (lgkmcnt 8: A1 drains under MFMA)
    bar();
    // ---- P2: stage B(kt+2) h0 -> buf cur ----
    if (kt + 2 < NT) { stgB(cur, 0, 0, kt+2); stgB(cur, 0, 1, kt+2); }
    bar();
    mma(aQ, 1, 1);          // waits A1 (lgkmcnt 0)
    bar();
    // ---- P3: stage B(kt+2) h1 ----
    if (kt + 2 < NT) { stgB(cur, 1, 0, kt+2); stgB(cur, 1, 1, kt+2); }
    bar();
    mma(aQ, 1, 0);          // all frags resident
    // tile-final: counted wait BEFORE barrier -> cross-wave landing guarantee
    if (kt < NT - 2) {
      asm volatile("s_waitcnt vmcnt(4)" ::: "memory");   // tile kt+1 landed
      bar();
    } else if (kt == NT - 2) {
      asm volatile("s_waitcnt vmcnt(0)" ::: "memory");   // drain A(NT-1)
      bar();
    }
  }

  // epilogue: C/D layout col = lane&15 (fr), row = fq*4 + reg
  #pragma unroll
  for (int nf = 0; nf < 4; ++nf) {
    const int col = n0 + wc*64 + nf*16 + fr;
    const float bv = bias[col];
    #pragma unroll
    for (int mf = 0; mf < 8; ++mf) {
      const int rowb = m0 + wr*128 + mf*16 + fq*4;
      #pragma unroll
      for (int r = 0; r < 4; ++r)
        C[(size_t)(rowb + r)*N + col] = acc[mf][nf][r] + bv;
    }
  }
}

extern "C" void kernel_launch(void* const* d_in, const int* in_sizes, int n_in,
                              void* d_out, int out_size, void* d_ws, size_t ws_size,
                              hipStream_t stream) {
  const float* x      = (const float*)d_in[0];   // (2,2048,4096)
  const float* W      = (const float*)d_in[1];   // (4096,4096)
  const float* bias   = (const float*)d_in[2];   // (4096)
  const float* boft_R = (const float*)d_in[3];   // (2,64,64,64)
  const float* boft_s = (const float*)d_in[4];   // (4096,1)
  float* out = (float*)d_out;

  char* ws = (char*)d_ws;
  float* Q    = (float*)ws;                        //  2 MB (128*64*64 f32)
  u16*   rotb = (u16*)  (ws + ((size_t)2  << 20)); //  1 MB (32*128*128 bf16)
  u16*   xb   = (u16*)  (ws + ((size_t)4  << 20)); // 32 MB
  u16*   swb  = (u16*)  (ws + ((size_t)36 << 20)); // 32 MB

  cayley_kernel  <<<128, 256, 0, stream>>>(boft_R, Q);
  rotbuild_kernel<<<32, 256, 0, stream>>>(Q, rotb);
  wtrans_kernel  <<<dim3(32, 32), 256, 0, stream>>>(W, rotb, boft_s, swb);
  cvt_kernel     <<<(16777216/8)/256, 256, 0, stream>>>(x, xb);
  gemm_kernel    <<<256, 512, 0, stream>>>(xb, swb, bias, out);
}

// Round 10
// 197.646 us; speedup vs baseline: 1.1295x; 1.1295x over previous
//
#include <hip/hip_runtime.h>

typedef unsigned short u16;
typedef unsigned int   u32;
typedef __attribute__((ext_vector_type(4))) float f32x4;
typedef __attribute__((ext_vector_type(8))) short bf16x8;
typedef __attribute__((ext_vector_type(4))) unsigned short u16x4;
typedef __attribute__((ext_vector_type(8))) unsigned short u16x8;

__device__ __forceinline__ u16 f2bf(float f) {
  union { float f; u32 u; } v; v.f = f;
  u32 r = v.u + 0x7FFFu + ((v.u >> 16) & 1u);   // round-to-nearest-even
  return (u16)(r >> 16);
}

__device__ __forceinline__ float bcast(float v, int l) {
  return __uint_as_float(__builtin_amdgcn_readlane(__float_as_uint(v), l));
}

// ---------------- Kernel 1: Cayley Q = 2*(I+S)^-1 - I, S = 0.5(R - R^T) ----
__global__ __launch_bounds__(256, 1) void cayley_kernel(
    const float* __restrict__ R, float* __restrict__ Q) {
  const int b  = blockIdx.x;
  const int t  = threadIdx.x;
  const int j  = t & 63;                // column owner (lane)
  const int iw = t >> 6;                // wave = row-block owner
  __shared__ float Rl[64][65];          // staged R (padded: transpose-read free)
  __shared__ float prow[2][2][64];      // [k parity][A|B][j]
  const float* Rb = R + (size_t)b * 4096;
  for (int idx = t; idx < 4096; idx += 256)
    Rl[idx >> 6][idx & 63] = Rb[idx];
  __syncthreads();
  float Ac[16], Bc[16];                 // A[16iw+i'][j], B[16iw+i'][j]
  #pragma unroll
  for (int i2 = 0; i2 < 16; ++i2) {
    const int i = iw*16 + i2;
    float s = 0.5f * (Rl[i][j] - Rl[j][i]);
    Ac[i2] = (i == j) ? (1.0f + s) : s;
    Bc[i2] = (i == j) ? 1.0f : 0.0f;
  }
  __syncthreads();
  #pragma unroll
  for (int kb = 0; kb < 4; ++kb) {
    #pragma unroll
    for (int kp = 0; kp < 16; ++kp) {
      const int k = kb*16 + kp;         // compile-time constant
      if (iw == kb) {                   // wave-uniform: pivot wave scales row k
        float pinv = 1.0f / bcast(Ac[kp], k);
        float ar = Ac[kp] * pinv;
        float br = Bc[kp] * pinv;
        Ac[kp] = ar; Bc[kp] = br;
        prow[k & 1][0][j] = ar;
        prow[k & 1][1][j] = br;
      }
      __syncthreads();
      const float ar = prow[k & 1][0][j];
      const float br = prow[k & 1][1][j];
      #pragma unroll
      for (int i2 = 0; i2 < 16; ++i2) { // eliminate own rows (static idx)
        float f = bcast(Ac[i2], k);     // A[16iw+i2][k], pre-update (lockstep)
        if (iw == kb && i2 == kp) f = 0.0f;   // pivot row preserved
        Ac[i2] -= f * ar;
        Bc[i2] -= f * br;
      }
    }
  }
  float* Qb = Q + (size_t)b * 4096;
  #pragma unroll
  for (int i2 = 0; i2 < 16; ++i2) {
    const int i = iw*16 + i2;
    Qb[i*64 + j] = 2.0f * Bc[i2] - ((i == j) ? 1.0f : 0.0f);
  }
}

// ---------------- Kernel 2: rot superblocks -> bf16 ------------------------
__global__ __launch_bounds__(256) void rotbuild_kernel(
    const float* __restrict__ Q, u16* __restrict__ rotb) {
  const int s = blockIdx.x;
  const int t = threadIdx.x;
  __shared__ float Q1l[2][64][65];      // padded
  __shared__ f32x4 Q0l[2][64][16];      // [dh][k][c4]
  const float* Q0g = Q + (size_t)(2*s) * 4096;        // factor 0: blocks 2s,2s+1
  const float* Q1g = Q + (size_t)(64 + 2*s) * 4096;   // factor 1 starts at block 64
  for (int i = t; i < 2*4096; i += 256) {
    int e = i >> 12, r = (i >> 6) & 63, c = i & 63;
    Q1l[e][r][c] = Q1g[i];
    ((float*)&Q0l[e][r][0])[c] = Q0g[i];
  }
  __syncthreads();
  const int a_l = t & 127;
  const int dh  = t >> 7;               // c-half this thread fills
  const int g   = a_l >> 5;             // local butterfly perm (involution)
  const int pa  = a_l + ((g == 1) ? 32 : (g == 2) ? -32 : 0);
  const int e = pa >> 6, pa64 = pa & 63;
  float q1v[32];
  #pragma unroll
  for (int jj = 0; jj < 32; ++jj) q1v[jj] = Q1l[e][pa64][dh*32 + jj];
  f32x4 acc4[16] = {};
  #pragma unroll
  for (int jj = 0; jj < 32; ++jj) {
    #pragma unroll
    for (int c4 = 0; c4 < 16; ++c4)
      acc4[c4] += q1v[jj] * Q0l[dh][e*32 + jj][c4];   // broadcast LDS read
  }
  u16* dst = rotb + (size_t)s*16384 + (size_t)a_l*128 + dh*64;
  #pragma unroll
  for (int c4 = 0; c4 < 16; ++c4) {
    u16x4 o;
    o.x = f2bf(acc4[c4].x); o.y = f2bf(acc4[c4].y);
    o.z = f2bf(acc4[c4].z); o.w = f2bf(acc4[c4].w);
    *(u16x4*)&dst[c4*4] = o;
  }
}

// ---------------- Kernel 3: SW = (W @ rot^T) * s -> bf16, MFMA -------------
__global__ __launch_bounds__(256) void wtrans_kernel(
    const float* __restrict__ W, const u16* __restrict__ rotb,
    const float* __restrict__ sscale, u16* __restrict__ SW) {
  const int rt = blockIdx.x;            // row tile 0..31
  const int s  = blockIdx.y;            // superblock 0..31
  const int t  = threadIdx.x;
  __shared__ u16 Asw[128*128];          // W tile bf16, swizzled
  __shared__ u16 Bsw[128*128];          // rot_s bf16, swizzled
  // stage A: granule g: row=g>>5, gc=g&31 (f32x4). Coalesced 16B/lane.
  #pragma unroll
  for (int p = 0; p < 16; ++p) {
    const int g = p*256 + t;
    const int row = g >> 5, gc = g & 31;
    float4 v = *(const float4*)(W + (size_t)(rt*128 + row)*4096 + s*128 + gc*4);
    u16x4 o;
    o.x = f2bf(v.x); o.y = f2bf(v.y); o.z = f2bf(v.z); o.w = f2bf(v.w);
    const int chunk = (gc >> 1) ^ (row & 7);
    *(u16x4*)&Asw[row*128 + chunk*8 + (gc & 1)*4] = o;
  }
  // stage B: granule g: row=g>>4, ch=g&15 (u16x8). Coalesced 16B/lane.
  const u16* rsrc = rotb + (size_t)s*16384;
  #pragma unroll
  for (int p = 0; p < 8; ++p) {
    const int g = p*256 + t;
    const int row = g >> 4, ch = g & 15;
    u16x8 v = *(const u16x8*)(rsrc + row*128 + ch*8);
    *(u16x8*)&Bsw[row*128 + ((ch ^ (row & 7))*8)] = v;
  }
  __syncthreads();
  const int w = t >> 6, l = t & 63;
  const int fr = l & 15, fq = l >> 4;
  const int wm = (w >> 1)*64, wn = (w & 1)*64;
  f32x4 acc[4][4] = {};
  #pragma unroll
  for (int ks = 0; ks < 4; ++ks) {
    bf16x8 af[4], bfr[4];
    #pragma unroll
    for (int m = 0; m < 4; ++m)
      af[m] = *(const bf16x8*)&Asw[(wm + m*16 + fr)*128 + (((ks*4 + fq) ^ (fr & 7))*8)];
    #pragma unroll
    for (int n = 0; n < 4; ++n)
      bfr[n] = *(const bf16x8*)&Bsw[(wn + n*16 + fr)*128 + (((ks*4 + fq) ^ (fr & 7))*8)];
    #pragma unroll
    for (int m = 0; m < 4; ++m)
      #pragma unroll
      for (int n = 0; n < 4; ++n)
        acc[m][n] = __builtin_amdgcn_mfma_f32_16x16x32_bf16(
            af[m], bfr[n], acc[m][n], 0, 0, 0);
  }
  // epilogue: C/D col = fr (output col), row = fq*4 + reg; scale by boft_s
  #pragma unroll
  for (int m = 0; m < 4; ++m) {
    #pragma unroll
    for (int r = 0; r < 4; ++r) {
      const int row = rt*128 + wm + m*16 + fq*4 + r;
      const float sc = sscale[row];
      #pragma unroll
      for (int n = 0; n < 4; ++n) {
        const int col = s*128 + wn + n*16 + fr;
        SW[(size_t)row*4096 + col] = f2bf(acc[m][n][r] * sc);
      }
    }
  }
}

// ---------------- Kernel 4: x f32 -> bf16 ----------------------------------
__global__ __launch_bounds__(256) void cvt_kernel(
    const float* __restrict__ x, u16* __restrict__ xb) {
  const size_t i = (size_t)blockIdx.x * 256 + threadIdx.x;  // 8 elems/thread
  const float4* p = (const float4*)x + i*2;
  float4 a = p[0], b = p[1];
  u16x8 o;
  o[0] = f2bf(a.x); o[1] = f2bf(a.y); o[2] = f2bf(a.z); o[3] = f2bf(a.w);
  o[4] = f2bf(b.x); o[5] = f2bf(b.y); o[6] = f2bf(b.z); o[7] = f2bf(b.w);
  *(u16x8*)(xb + i*8) = o;
}

// ---------------- Kernel 5: bf16 MFMA GEMM — 256^2, 2-tile-deep prefetch ---
// R9 post-mortem: manual frag read-ahead regressed (compiler scheds better);
// reverted to R8 read structure. REAL stall (R8 38.8% util): A staged only
// 1 tile ahead -> tile-final vmcnt waited on loads issued ~450cyc ago
// (< 900cyc HBM latency) = guaranteed stall/tile. Now BOTH A and B stage
// 2 tiles ahead into buf cur (B region free after P1, A region after P2);
// vmcnt(8) waits on loads issued ~1.25 tiles (~1150cyc) earlier -> no stall.
#define GLDS16(g, l)                                                   \
  __builtin_amdgcn_global_load_lds(                                    \
      (const __attribute__((address_space(1))) void*)(g),              \
      (__attribute__((address_space(3))) void*)(l), 16, 0, 0)

__device__ __forceinline__ void bar() {
  asm volatile("" ::: "memory");
  __builtin_amdgcn_s_barrier();
  asm volatile("" ::: "memory");
}

__global__ __launch_bounds__(512, 2) void gemm_kernel(
    const u16* __restrict__ A, const u16* __restrict__ B,
    const float* __restrict__ bias, float* __restrict__ C) {
  constexpr int K = 4096, N = 4096, NT = 64;   // K-tiles of BK=64
  __shared__ u16 As[2*256*64];                 // [buf][256 rows][64 cols]
  __shared__ u16 Bs[2*256*64];
  const int t = threadIdx.x;
  const int w = t >> 6, l = t & 63;
  const int wr = w >> 2, wc = w & 3;            // wave -> (2 x 4) grid
  const int fr = l & 15, fq = l >> 4;

  // XCD-aware swizzle (nwg=256, %8==0 -> simple bijective form)
  const int wg  = blockIdx.x;
  const int swz = (wg & 7) * 32 + (wg >> 3);
  const int m0  = (swz & 15) * 256, n0 = (swz >> 4) * 256;

  // staging: thread t fills LDS-linear granule (row = w*8 + (l>>3), c = l&7);
  // that slot must hold logical col (l&7) ^ (row&7)  [row&7 = (l>>3)&7].
  const int grow = w*8 + (l >> 3);                       // + o*64 + half*128
  const int gcol = ((l & 7) ^ ((l >> 3) & 7)) * 8;
  const u16* aS = A + (size_t)(m0 + grow) * K + gcol;
  const u16* bS = B + (size_t)(n0 + grow) * K + gcol;
  const int wLds = w * 512;                               // u16, wave-uniform

  // read: logical col = fq + 4*ks; stored col = (fq ^ (fr&7)) ^ 4*ks
  const int colbase = (fq ^ (fr & 7)) * 8;                // u16; ks flips ^32
  const u16* aRd = As + (wr*128 + fr)*64;  // + cur*16384 + mf*1024 + (colbase^(ks<<5))
  const u16* bRd = Bs + (wc*64  + fr)*64;

  auto stgA = [&](int buf, int half, int o, int kt_) {
    GLDS16(aS + (size_t)(half*128 + o*64) * K + (size_t)kt_*64,
           As + buf*16384 + half*8192 + o*4096 + wLds);
  };
  auto stgB = [&](int buf, int half, int o, int kt_) {
    GLDS16(bS + (size_t)(half*128 + o*64) * K + (size_t)kt_*64,
           Bs + buf*16384 + half*8192 + o*4096 + wLds);
  };

  f32x4 acc[8][4] = {};
  bf16x8 aFr[4][2], bFr[4][2];

  // prologue: tile0 -> buf0, tile1 -> buf1 (8 loads each, B then A)
  stgB(0,0,0,0); stgB(0,0,1,0); stgB(0,1,0,0); stgB(0,1,1,0);
  stgA(0,0,0,0); stgA(0,0,1,0); stgA(0,1,0,0); stgA(0,1,1,0);
  stgB(1,0,0,1); stgB(1,0,1,1); stgB(1,1,0,1); stgB(1,1,1,1);
  stgA(1,0,0,1); stgA(1,0,1,1); stgA(1,1,0,1); stgA(1,1,1,1);
  asm volatile("s_waitcnt vmcnt(8)" ::: "memory");   // tile0 landed, tile1 in flight
  bar();

  for (int kt = 0; kt < NT; ++kt) {
    const int cur = kt & 1;
    const u16* aC = aRd + cur*16384;
    const u16* bC = bRd + cur*16384;
    auto lda = [&](int mh) {
      #pragma unroll
      for (int m = 0; m < 4; ++m)
        #pragma unroll
        for (int ks = 0; ks < 2; ++ks)
          aFr[m][ks] = *(const bf16x8*)(aC + (mh*4 + m)*1024 + (colbase ^ (ks << 5)));
    };
    auto ldb = [&](int nh) {
      #pragma unroll
      for (int n = 0; n < 2; ++n)
        #pragma unroll
        for (int ks = 0; ks < 2; ++ks)
          bFr[nh*2 + n][ks] = *(const bf16x8*)(bC + (nh*2 + n)*1024 + (colbase ^ (ks << 5)));
    };
    auto mma = [&](int mh, int nh) {
      __builtin_amdgcn_s_setprio(1);
      #pragma unroll
      for (int m = 0; m < 4; ++m)
        #pragma unroll
        for (int n = 0; n < 2; ++n)
          #pragma unroll
          for (int ks = 0; ks < 2; ++ks)
            acc[mh*4 + m][nh*2 + n] = __builtin_amdgcn_mfma_f32_16x16x32_bf16(
                aFr[m][ks], bFr[nh*2 + n][ks], acc[mh*4 + m][nh*2 + n], 0, 0, 0);
      __builtin_amdgcn_s_setprio(0);
    };
    // ---- P0 ----
    lda(0); ldb(0);
    bar();
    mma(0, 0);
    bar();
    // ---- P1 ----
    ldb(1);
    bar();
    mma(0, 1);
    bar();
    // ---- P2: B region of cur fully read (P1) -> stage B(kt+2) into cur ----
    if (kt + 2 < NT) { stgB(cur,0,0,kt+2); stgB(cur,0,1,kt+2);
                       stgB(cur,1,0,kt+2); stgB(cur,1,1,kt+2); }
    lda(1);
    bar();
    mma(1, 1);
    bar();
    // ---- P3: A region of cur fully read (P2) -> stage A(kt+2) into cur ----
    if (kt + 2 < NT) { stgA(cur,0,0,kt+2); stgA(cur,0,1,kt+2);
                       stgA(cur,1,0,kt+2); stgA(cur,1,1,kt+2); }
    bar();
    mma(1, 0);
    // tile-final: wait tile kt+1 landed (issued ~1.25 tiles ago -> no stall)
    if (kt < NT - 2) {
      asm volatile("s_waitcnt vmcnt(8)" ::: "memory");   // 8 = kt+2 batch in flight
    } else if (kt == NT - 2) {
      asm volatile("s_waitcnt vmcnt(0)" ::: "memory");   // drain last batch
    }
    bar();
  }

  // epilogue: C/D layout col = lane&15 (fr), row = fq*4 + reg
  #pragma unroll
  for (int nf = 0; nf < 4; ++nf) {
    const int col = n0 + wc*64 + nf*16 + fr;
    const float bv = bias[col];
    #pragma unroll
    for (int mf = 0; mf < 8; ++mf) {
      const int rowb = m0 + wr*128 + mf*16 + fq*4;
      #pragma unroll
      for (int r = 0; r < 4; ++r)
        C[(size_t)(rowb + r)*N + col] = acc[mf][nf][r] + bv;
    }
  }
}

extern "C" void kernel_launch(void* const* d_in, const int* in_sizes, int n_in,
                              void* d_out, int out_size, void* d_ws, size_t ws_size,
                              hipStream_t stream) {
  const float* x      = (const float*)d_in[0];   // (2,2048,4096)
  const float* W      = (const float*)d_in[1];   // (4096,4096)
  const float* bias   = (const float*)d_in[2];   // (4096)
  const float* boft_R = (const float*)d_in[3];   // (2,64,64,64)
  const float* boft_s = (const float*)d_in[4];   // (4096,1)
  float* out = (float*)d_out;

  char* ws = (char*)d_ws;
  float* Q    = (float*)ws;                        //  2 MB (128*64*64 f32)
  u16*   rotb = (u16*)  (ws + ((size_t)2  << 20)); //  1 MB (32*128*128 bf16)
  u16*   xb   = (u16*)  (ws + ((size_t)4  << 20)); // 32 MB
  u16*   swb  = (u16*)  (ws + ((size_t)36 << 20)); // 32 MB

  cayley_kernel  <<<128, 256, 0, stream>>>(boft_R, Q);
  rotbuild_kernel<<<32, 256, 0, stream>>>(Q, rotb);
  wtrans_kernel  <<<dim3(32, 32), 256, 0, stream>>>(W, rotb, boft_s, swb);
  cvt_kernel     <<<(16777216/8)/256, 256, 0, stream>>>(x, xb);
  gemm_kernel    <<<256, 512, 0, stream>>>(xb, swb, bias, out);
}

// Round 11
// 193.156 us; speedup vs baseline: 1.1558x; 1.0232x over previous
//
#include <hip/hip_runtime.h>

typedef unsigned short u16;
typedef unsigned int   u32;
typedef __attribute__((ext_vector_type(4))) float f32x4;
typedef __attribute__((ext_vector_type(8))) short bf16x8;
typedef __attribute__((ext_vector_type(4))) unsigned short u16x4;
typedef __attribute__((ext_vector_type(8))) unsigned short u16x8;

__device__ __forceinline__ u16 f2bf(float f) {
  union { float f; u32 u; } v; v.f = f;
  u32 r = v.u + 0x7FFFu + ((v.u >> 16) & 1u);   // round-to-nearest-even
  return (u16)(r >> 16);
}

__device__ __forceinline__ float bcast(float v, int l) {
  return __uint_as_float(__builtin_amdgcn_readlane(__float_as_uint(v), l));
}

// ---------------- Kernel 1: Cayley Q = 2*(I+S)^-1 - I, S = 0.5(R - R^T) ----
__global__ __launch_bounds__(256, 1) void cayley_kernel(
    const float* __restrict__ R, float* __restrict__ Q) {
  const int b  = blockIdx.x;
  const int t  = threadIdx.x;
  const int j  = t & 63;                // column owner (lane)
  const int iw = t >> 6;                // wave = row-block owner
  __shared__ float Rl[64][65];          // staged R (padded: transpose-read free)
  __shared__ float prow[2][2][64];      // [k parity][A|B][j]
  const float* Rb = R + (size_t)b * 4096;
  for (int idx = t; idx < 4096; idx += 256)
    Rl[idx >> 6][idx & 63] = Rb[idx];
  __syncthreads();
  float Ac[16], Bc[16];                 // A[16iw+i'][j], B[16iw+i'][j]
  #pragma unroll
  for (int i2 = 0; i2 < 16; ++i2) {
    const int i = iw*16 + i2;
    float s = 0.5f * (Rl[i][j] - Rl[j][i]);
    Ac[i2] = (i == j) ? (1.0f + s) : s;
    Bc[i2] = (i == j) ? 1.0f : 0.0f;
  }
  __syncthreads();
  #pragma unroll
  for (int kb = 0; kb < 4; ++kb) {
    #pragma unroll
    for (int kp = 0; kp < 16; ++kp) {
      const int k = kb*16 + kp;         // compile-time constant
      if (iw == kb) {                   // wave-uniform: pivot wave scales row k
        float pinv = 1.0f / bcast(Ac[kp], k);
        float ar = Ac[kp] * pinv;
        float br = Bc[kp] * pinv;
        Ac[kp] = ar; Bc[kp] = br;
        prow[k & 1][0][j] = ar;
        prow[k & 1][1][j] = br;
      }
      __syncthreads();
      const float ar = prow[k & 1][0][j];
      const float br = prow[k & 1][1][j];
      #pragma unroll
      for (int i2 = 0; i2 < 16; ++i2) { // eliminate own rows (static idx)
        float f = bcast(Ac[i2], k);     // A[16iw+i2][k], pre-update (lockstep)
        if (iw == kb && i2 == kp) f = 0.0f;   // pivot row preserved
        Ac[i2] -= f * ar;
        Bc[i2] -= f * br;
      }
    }
  }
  float* Qb = Q + (size_t)b * 4096;
  #pragma unroll
  for (int i2 = 0; i2 < 16; ++i2) {
    const int i = iw*16 + i2;
    Qb[i*64 + j] = 2.0f * Bc[i2] - ((i == j) ? 1.0f : 0.0f);
  }
}

// ---------------- Kernel 2: rot superblocks -> bf16 ------------------------
__global__ __launch_bounds__(256) void rotbuild_kernel(
    const float* __restrict__ Q, u16* __restrict__ rotb) {
  const int s = blockIdx.x;
  const int t = threadIdx.x;
  __shared__ float Q1l[2][64][65];      // padded
  __shared__ f32x4 Q0l[2][64][16];      // [dh][k][c4]
  const float* Q0g = Q + (size_t)(2*s) * 4096;        // factor 0: blocks 2s,2s+1
  const float* Q1g = Q + (size_t)(64 + 2*s) * 4096;   // factor 1 starts at block 64
  for (int i = t; i < 2*4096; i += 256) {
    int e = i >> 12, r = (i >> 6) & 63, c = i & 63;
    Q1l[e][r][c] = Q1g[i];
    ((float*)&Q0l[e][r][0])[c] = Q0g[i];
  }
  __syncthreads();
  const int a_l = t & 127;
  const int dh  = t >> 7;               // c-half this thread fills
  const int g   = a_l >> 5;             // local butterfly perm (involution)
  const int pa  = a_l + ((g == 1) ? 32 : (g == 2) ? -32 : 0);
  const int e = pa >> 6, pa64 = pa & 63;
  float q1v[32];
  #pragma unroll
  for (int jj = 0; jj < 32; ++jj) q1v[jj] = Q1l[e][pa64][dh*32 + jj];
  f32x4 acc4[16] = {};
  #pragma unroll
  for (int jj = 0; jj < 32; ++jj) {
    #pragma unroll
    for (int c4 = 0; c4 < 16; ++c4)
      acc4[c4] += q1v[jj] * Q0l[dh][e*32 + jj][c4];   // broadcast LDS read
  }
  u16* dst = rotb + (size_t)s*16384 + (size_t)a_l*128 + dh*64;
  #pragma unroll
  for (int c4 = 0; c4 < 16; ++c4) {
    u16x4 o;
    o.x = f2bf(acc4[c4].x); o.y = f2bf(acc4[c4].y);
    o.z = f2bf(acc4[c4].z); o.w = f2bf(acc4[c4].w);
    *(u16x4*)&dst[c4*4] = o;
  }
}

// ---------------- Kernel 3: SW = (W @ rot^T) * s -> bf16, MFMA -------------
__global__ __launch_bounds__(256) void wtrans_kernel(
    const float* __restrict__ W, const u16* __restrict__ rotb,
    const float* __restrict__ sscale, u16* __restrict__ SW) {
  const int rt = blockIdx.x;            // row tile 0..31
  const int s  = blockIdx.y;            // superblock 0..31
  const int t  = threadIdx.x;
  __shared__ u16 Asw[128*128];          // W tile bf16, swizzled
  __shared__ u16 Bsw[128*128];          // rot_s bf16, swizzled
  // stage A: granule g: row=g>>5, gc=g&31 (f32x4). Coalesced 16B/lane.
  #pragma unroll
  for (int p = 0; p < 16; ++p) {
    const int g = p*256 + t;
    const int row = g >> 5, gc = g & 31;
    float4 v = *(const float4*)(W + (size_t)(rt*128 + row)*4096 + s*128 + gc*4);
    u16x4 o;
    o.x = f2bf(v.x); o.y = f2bf(v.y); o.z = f2bf(v.z); o.w = f2bf(v.w);
    const int chunk = (gc >> 1) ^ (row & 7);
    *(u16x4*)&Asw[row*128 + chunk*8 + (gc & 1)*4] = o;
  }
  // stage B: granule g: row=g>>4, ch=g&15 (u16x8). Coalesced 16B/lane.
  const u16* rsrc = rotb + (size_t)s*16384;
  #pragma unroll
  for (int p = 0; p < 8; ++p) {
    const int g = p*256 + t;
    const int row = g >> 4, ch = g & 15;
    u16x8 v = *(const u16x8*)(rsrc + row*128 + ch*8);
    *(u16x8*)&Bsw[row*128 + ((ch ^ (row & 7))*8)] = v;
  }
  __syncthreads();
  const int w = t >> 6, l = t & 63;
  const int fr = l & 15, fq = l >> 4;
  const int wm = (w >> 1)*64, wn = (w & 1)*64;
  f32x4 acc[4][4] = {};
  #pragma unroll
  for (int ks = 0; ks < 4; ++ks) {
    bf16x8 af[4], bfr[4];
    #pragma unroll
    for (int m = 0; m < 4; ++m)
      af[m] = *(const bf16x8*)&Asw[(wm + m*16 + fr)*128 + (((ks*4 + fq) ^ (fr & 7))*8)];
    #pragma unroll
    for (int n = 0; n < 4; ++n)
      bfr[n] = *(const bf16x8*)&Bsw[(wn + n*16 + fr)*128 + (((ks*4 + fq) ^ (fr & 7))*8)];
    #pragma unroll
    for (int m = 0; m < 4; ++m)
      #pragma unroll
      for (int n = 0; n < 4; ++n)
        acc[m][n] = __builtin_amdgcn_mfma_f32_16x16x32_bf16(
            af[m], bfr[n], acc[m][n], 0, 0, 0);
  }
  // epilogue: C/D col = fr (output col), row = fq*4 + reg; scale by boft_s
  #pragma unroll
  for (int m = 0; m < 4; ++m) {
    #pragma unroll
    for (int r = 0; r < 4; ++r) {
      const int row = rt*128 + wm + m*16 + fq*4 + r;
      const float sc = sscale[row];
      #pragma unroll
      for (int n = 0; n < 4; ++n) {
        const int col = s*128 + wn + n*16 + fr;
        SW[(size_t)row*4096 + col] = f2bf(acc[m][n][r] * sc);
      }
    }
  }
}

// ---------------- Kernel 4: x f32 -> bf16 ----------------------------------
__global__ __launch_bounds__(256) void cvt_kernel(
    const float* __restrict__ x, u16* __restrict__ xb) {
  const size_t i = (size_t)blockIdx.x * 256 + threadIdx.x;  // 8 elems/thread
  const float4* p = (const float4*)x + i*2;
  float4 a = p[0], b = p[1];
  u16x8 o;
  o[0] = f2bf(a.x); o[1] = f2bf(a.y); o[2] = f2bf(a.z); o[3] = f2bf(a.w);
  o[4] = f2bf(b.x); o[5] = f2bf(b.y); o[6] = f2bf(b.z); o[7] = f2bf(b.w);
  *(u16x8*)(xb + i*8) = o;
}

// ---------------- Kernel 5: bf16 MFMA GEMM — tail-read schedule ------------
// R11: cycle ledger showed reads⟂MFMA serialization (2304+2065 cyc/tile).
// Fix with ZERO new registers: every frag read moves to the tail of the
// phase whose MFMA just freed those regs:
//   P0: A0/B0 reads interleaved with mma(0,0) at frag granularity; tail: B1
//   P1: mma(0,1) [B1 pre-read]; tail: A1 into aFr (freed by mma(0,1))
//   P2: stageB(kt+2); mma(1,1) [A1 drains under P1-tail+bar]
//   P3: stageA(kt+2); mma(1,0) [all resident]; vmcnt(8); bar
// One barrier per phase (4/tile, was 8) — WAR orderings desk-checked:
// B-reads drain before P1-end bar -> stgB@P2 safe; A-reads before P2-end
// -> stgA@P3 safe. Raw s_barrier does NOT drain lgkm -> tail reads cross it.
#define GLDS16(g, l)                                                   \
  __builtin_amdgcn_global_load_lds(                                    \
      (const __attribute__((address_space(1))) void*)(g),              \
      (__attribute__((address_space(3))) void*)(l), 16, 0, 0)

__device__ __forceinline__ void bar() {
  asm volatile("" ::: "memory");
  __builtin_amdgcn_s_barrier();
  asm volatile("" ::: "memory");
}

__global__ __launch_bounds__(512, 2) void gemm_kernel(
    const u16* __restrict__ A, const u16* __restrict__ B,
    const float* __restrict__ bias, float* __restrict__ C) {
  constexpr int K = 4096, N = 4096, NT = 64;   // K-tiles of BK=64
  __shared__ u16 As[2*256*64];                 // [buf][256 rows][64 cols]
  __shared__ u16 Bs[2*256*64];
  const int t = threadIdx.x;
  const int w = t >> 6, l = t & 63;
  const int wr = w >> 2, wc = w & 3;            // wave -> (2 x 4) grid
  const int fr = l & 15, fq = l >> 4;

  // XCD-aware swizzle (nwg=256, %8==0 -> simple bijective form)
  const int wg  = blockIdx.x;
  const int swz = (wg & 7) * 32 + (wg >> 3);
  const int m0  = (swz & 15) * 256, n0 = (swz >> 4) * 256;

  // staging: thread t fills LDS-linear granule (row = w*8 + (l>>3), c = l&7);
  // that slot must hold logical col (l&7) ^ (row&7)  [row&7 = (l>>3)&7].
  const int grow = w*8 + (l >> 3);                       // + o*64 + half*128
  const int gcol = ((l & 7) ^ ((l >> 3) & 7)) * 8;
  const u16* aS = A + (size_t)(m0 + grow) * K + gcol;
  const u16* bS = B + (size_t)(n0 + grow) * K + gcol;
  const int wLds = w * 512;                               // u16, wave-uniform

  // read: logical col = fq + 4*ks; stored col = (fq ^ (fr&7)) ^ 4*ks
  const int colbase = (fq ^ (fr & 7)) * 8;                // u16; ks flips ^32
  const u16* aRd = As + (wr*128 + fr)*64;  // + cur*16384 + mf*1024 + (colbase^(ks<<5))
  const u16* bRd = Bs + (wc*64  + fr)*64;

  auto stgA = [&](int buf, int half, int o, int kt_) {
    GLDS16(aS + (size_t)(half*128 + o*64) * K + (size_t)kt_*64,
           As + buf*16384 + half*8192 + o*4096 + wLds);
  };
  auto stgB = [&](int buf, int half, int o, int kt_) {
    GLDS16(bS + (size_t)(half*128 + o*64) * K + (size_t)kt_*64,
           Bs + buf*16384 + half*8192 + o*4096 + wLds);
  };

  f32x4 acc[8][4] = {};
  bf16x8 aFr[4][2];          // holds A0 during P0-P1, A1 during P2-P3
  bf16x8 bFr[4][2];          // n=0,1: B0 (used P0,P3); n=2,3: B1 (used P1,P2)

  // prologue: tile0 -> buf0, tile1 -> buf1 (B then A per tile)
  stgB(0,0,0,0); stgB(0,0,1,0); stgB(0,1,0,0); stgB(0,1,1,0);
  stgA(0,0,0,0); stgA(0,0,1,0); stgA(0,1,0,0); stgA(0,1,1,0);
  stgB(1,0,0,1); stgB(1,0,1,1); stgB(1,1,0,1); stgB(1,1,1,1);
  stgA(1,0,0,1); stgA(1,0,1,1); stgA(1,1,0,1); stgA(1,1,1,1);
  asm volatile("s_waitcnt vmcnt(8)" ::: "memory");   // tile0 landed, tile1 in flight
  bar();

  for (int kt = 0; kt < NT; ++kt) {
    const int cur = kt & 1;
    const u16* aC = aRd + cur*16384;
    const u16* bC = bRd + cur*16384;

    // ---- P0: B0 reads, then per-m {A0-frag read + 4 mma} ; tail: B1 ------
    __builtin_amdgcn_s_setprio(1);
    bFr[0][0] = *(const bf16x8*)(bC + 0*1024 + colbase);
    bFr[0][1] = *(const bf16x8*)(bC + 0*1024 + (colbase ^ 32));
    bFr[1][0] = *(const bf16x8*)(bC + 1*1024 + colbase);
    bFr[1][1] = *(const bf16x8*)(bC + 1*1024 + (colbase ^ 32));
    #pragma unroll
    for (int m = 0; m < 4; ++m) {
      aFr[m][0] = *(const bf16x8*)(aC + m*1024 + colbase);
      aFr[m][1] = *(const bf16x8*)(aC + m*1024 + (colbase ^ 32));
      acc[m][0] = __builtin_amdgcn_mfma_f32_16x16x32_bf16(aFr[m][0], bFr[0][0], acc[m][0], 0,0,0);
      acc[m][0] = __builtin_amdgcn_mfma_f32_16x16x32_bf16(aFr[m][1], bFr[0][1], acc[m][0], 0,0,0);
      acc[m][1] = __builtin_amdgcn_mfma_f32_16x16x32_bf16(aFr[m][0], bFr[1][0], acc[m][1], 0,0,0);
      acc[m][1] = __builtin_amdgcn_mfma_f32_16x16x32_bf16(aFr[m][1], bFr[1][1], acc[m][1], 0,0,0);
    }
    __builtin_amdgcn_s_setprio(0);
    // tail: B1 reads (bFr[2..3] freed since prev P2)
    bFr[2][0] = *(const bf16x8*)(bC + 2*1024 + colbase);
    bFr[2][1] = *(const bf16x8*)(bC + 2*1024 + (colbase ^ 32));
    bFr[3][0] = *(const bf16x8*)(bC + 3*1024 + colbase);
    bFr[3][1] = *(const bf16x8*)(bC + 3*1024 + (colbase ^ 32));
    bar();

    // ---- P1: mma(0,1) ; tail: A1 into aFr (freed) ------------------------
    __builtin_amdgcn_s_setprio(1);
    #pragma unroll
    for (int m = 0; m < 4; ++m) {
      #pragma unroll
      for (int n = 2; n < 4; ++n) {
        acc[m][n] = __builtin_amdgcn_mfma_f32_16x16x32_bf16(aFr[m][0], bFr[n][0], acc[m][n], 0,0,0);
        acc[m][n] = __builtin_amdgcn_mfma_f32_16x16x32_bf16(aFr[m][1], bFr[n][1], acc[m][n], 0,0,0);
      }
    }
    __builtin_amdgcn_s_setprio(0);
    #pragma unroll
    for (int m = 0; m < 4; ++m) {
      aFr[m][0] = *(const bf16x8*)(aC + (4 + m)*1024 + colbase);
      aFr[m][1] = *(const bf16x8*)(aC + (4 + m)*1024 + (colbase ^ 32));
    }
    bar();

    // ---- P2: stage B(kt+2) ; mma(1,1) ------------------------------------
    if (kt + 2 < NT) { stgB(cur,0,0,kt+2); stgB(cur,0,1,kt+2);
                       stgB(cur,1,0,kt+2); stgB(cur,1,1,kt+2); }
    __builtin_amdgcn_s_setprio(1);
    #pragma unroll
    for (int m = 0; m < 4; ++m) {
      #pragma unroll
      for (int n = 2; n < 4; ++n) {
        acc[4+m][n] = __builtin_amdgcn_mfma_f32_16x16x32_bf16(aFr[m][0], bFr[n][0], acc[4+m][n], 0,0,0);
        acc[4+m][n] = __builtin_amdgcn_mfma_f32_16x16x32_bf16(aFr[m][1], bFr[n][1], acc[4+m][n], 0,0,0);
      }
    }
    __builtin_amdgcn_s_setprio(0);
    bar();

    // ---- P3: stage A(kt+2) ; mma(1,0) ; vmcnt ; bar ----------------------
    if (kt + 2 < NT) { stgA(cur,0,0,kt+2); stgA(cur,0,1,kt+2);
                       stgA(cur,1,0,kt+2); stgA(cur,1,1,kt+2); }
    __builtin_amdgcn_s_setprio(1);
    #pragma unroll
    for (int m = 0; m < 4; ++m) {
      #pragma unroll
      for (int n = 0; n < 2; ++n) {
        acc[4+m][n] = __builtin_amdgcn_mfma_f32_16x16x32_bf16(aFr[m][0], bFr[n][0], acc[4+m][n], 0,0,0);
        acc[4+m][n] = __builtin_amdgcn_mfma_f32_16x16x32_bf16(aFr[m][1], bFr[n][1], acc[4+m][n], 0,0,0);
      }
    }
    __builtin_amdgcn_s_setprio(0);
    // tile-final: per-wave counted wait, then barrier -> all-waves guarantee
    if (kt < NT - 2) {
      asm volatile("s_waitcnt vmcnt(8)" ::: "memory");   // tile kt+1 landed
    } else if (kt == NT - 2) {
      asm volatile("s_waitcnt vmcnt(0)" ::: "memory");   // drain last batch
    }
    bar();
  }

  // epilogue: C/D layout col = lane&15 (fr), row = fq*4 + reg
  #pragma unroll
  for (int nf = 0; nf < 4; ++nf) {
    const int col = n0 + wc*64 + nf*16 + fr;
    const float bv = bias[col];
    #pragma unroll
    for (int mf = 0; mf < 8; ++mf) {
      const int rowb = m0 + wr*128 + mf*16 + fq*4;
      #pragma unroll
      for (int r = 0; r < 4; ++r)
        C[(size_t)(rowb + r)*N + col] = acc[mf][nf][r] + bv;
    }
  }
}

extern "C" void kernel_launch(void* const* d_in, const int* in_sizes, int n_in,
                              void* d_out, int out_size, void* d_ws, size_t ws_size,
                              hipStream_t stream) {
  const float* x      = (const float*)d_in[0];   // (2,2048,4096)
  const float* W      = (const float*)d_in[1];   // (4096,4096)
  const float* bias   = (const float*)d_in[2];   // (4096)
  const float* boft_R = (const float*)d_in[3];   // (2,64,64,64)
  const float* boft_s = (const float*)d_in[4];   // (4096,1)
  float* out = (float*)d_out;

  char* ws = (char*)d_ws;
  float* Q    = (float*)ws;                        //  2 MB (128*64*64 f32)
  u16*   rotb = (u16*)  (ws + ((size_t)2  << 20)); //  1 MB (32*128*128 bf16)
  u16*   xb   = (u16*)  (ws + ((size_t)4  << 20)); // 32 MB
  u16*   swb  = (u16*)  (ws + ((size_t)36 << 20)); // 32 MB

  cayley_kernel  <<<128, 256, 0, stream>>>(boft_R, Q);
  rotbuild_kernel<<<32, 256, 0, stream>>>(Q, rotb);
  wtrans_kernel  <<<dim3(32, 32), 256, 0, stream>>>(W, rotb, boft_s, swb);
  cvt_kernel     <<<(16777216/8)/256, 256, 0, stream>>>(x, xb);
  gemm_kernel    <<<256, 512, 0, stream>>>(xb, swb, bias, out);
}

// Round 12
// 189.097 us; speedup vs baseline: 1.1806x; 1.0215x over previous
//
#include <hip/hip_runtime.h>

typedef unsigned short u16;
typedef unsigned int   u32;
typedef __attribute__((ext_vector_type(4))) float f32x4;
typedef __attribute__((ext_vector_type(8))) short bf16x8;
typedef __attribute__((ext_vector_type(4))) unsigned short u16x4;
typedef __attribute__((ext_vector_type(8))) unsigned short u16x8;

__device__ __forceinline__ u16 f2bf(float f) {
  union { float f; u32 u; } v; v.f = f;
  u32 r = v.u + 0x7FFFu + ((v.u >> 16) & 1u);   // round-to-nearest-even
  return (u16)(r >> 16);
}

__device__ __forceinline__ float bcast(float v, int l) {
  return __uint_as_float(__builtin_amdgcn_readlane(__float_as_uint(v), l));
}

// ---------------- Kernel 1: Cayley Q = 2*(I+S)^-1 - I, S = 0.5(R - R^T) ----
__global__ __launch_bounds__(256, 1) void cayley_kernel(
    const float* __restrict__ R, float* __restrict__ Q) {
  const int b  = blockIdx.x;
  const int t  = threadIdx.x;
  const int j  = t & 63;                // column owner (lane)
  const int iw = t >> 6;                // wave = row-block owner
  __shared__ float Rl[64][65];          // staged R (padded: transpose-read free)
  __shared__ float prow[2][2][64];      // [k parity][A|B][j]
  const float* Rb = R + (size_t)b * 4096;
  for (int idx = t; idx < 4096; idx += 256)
    Rl[idx >> 6][idx & 63] = Rb[idx];
  __syncthreads();
  float Ac[16], Bc[16];                 // A[16iw+i'][j], B[16iw+i'][j]
  #pragma unroll
  for (int i2 = 0; i2 < 16; ++i2) {
    const int i = iw*16 + i2;
    float s = 0.5f * (Rl[i][j] - Rl[j][i]);
    Ac[i2] = (i == j) ? (1.0f + s) : s;
    Bc[i2] = (i == j) ? 1.0f : 0.0f;
  }
  __syncthreads();
  #pragma unroll
  for (int kb = 0; kb < 4; ++kb) {
    #pragma unroll
    for (int kp = 0; kp < 16; ++kp) {
      const int k = kb*16 + kp;         // compile-time constant
      if (iw == kb) {                   // wave-uniform: pivot wave scales row k
        float pinv = 1.0f / bcast(Ac[kp], k);
        float ar = Ac[kp] * pinv;
        float br = Bc[kp] * pinv;
        Ac[kp] = ar; Bc[kp] = br;
        prow[k & 1][0][j] = ar;
        prow[k & 1][1][j] = br;
      }
      __syncthreads();
      const float ar = prow[k & 1][0][j];
      const float br = prow[k & 1][1][j];
      #pragma unroll
      for (int i2 = 0; i2 < 16; ++i2) { // eliminate own rows (static idx)
        float f = bcast(Ac[i2], k);     // A[16iw+i2][k], pre-update (lockstep)
        if (iw == kb && i2 == kp) f = 0.0f;   // pivot row preserved
        Ac[i2] -= f * ar;
        Bc[i2] -= f * br;
      }
    }
  }
  float* Qb = Q + (size_t)b * 4096;
  #pragma unroll
  for (int i2 = 0; i2 < 16; ++i2) {
    const int i = iw*16 + i2;
    Qb[i*64 + j] = 2.0f * Bc[i2] - ((i == j) ? 1.0f : 0.0f);
  }
}

// ---------------- Kernel 2: rot superblocks -> bf16 ------------------------
__global__ __launch_bounds__(256) void rotbuild_kernel(
    const float* __restrict__ Q, u16* __restrict__ rotb) {
  const int s = blockIdx.x;
  const int t = threadIdx.x;
  __shared__ float Q1l[2][64][65];      // padded
  __shared__ f32x4 Q0l[2][64][16];      // [dh][k][c4]
  const float* Q0g = Q + (size_t)(2*s) * 4096;        // factor 0: blocks 2s,2s+1
  const float* Q1g = Q + (size_t)(64 + 2*s) * 4096;   // factor 1 starts at block 64
  for (int i = t; i < 2*4096; i += 256) {
    int e = i >> 12, r = (i >> 6) & 63, c = i & 63;
    Q1l[e][r][c] = Q1g[i];
    ((float*)&Q0l[e][r][0])[c] = Q0g[i];
  }
  __syncthreads();
  const int a_l = t & 127;
  const int dh  = t >> 7;               // c-half this thread fills
  const int g   = a_l >> 5;             // local butterfly perm (involution)
  const int pa  = a_l + ((g == 1) ? 32 : (g == 2) ? -32 : 0);
  const int e = pa >> 6, pa64 = pa & 63;
  float q1v[32];
  #pragma unroll
  for (int jj = 0; jj < 32; ++jj) q1v[jj] = Q1l[e][pa64][dh*32 + jj];
  f32x4 acc4[16] = {};
  #pragma unroll
  for (int jj = 0; jj < 32; ++jj) {
    #pragma unroll
    for (int c4 = 0; c4 < 16; ++c4)
      acc4[c4] += q1v[jj] * Q0l[dh][e*32 + jj][c4];   // broadcast LDS read
  }
  u16* dst = rotb + (size_t)s*16384 + (size_t)a_l*128 + dh*64;
  #pragma unroll
  for (int c4 = 0; c4 < 16; ++c4) {
    u16x4 o;
    o.x = f2bf(acc4[c4].x); o.y = f2bf(acc4[c4].y);
    o.z = f2bf(acc4[c4].z); o.w = f2bf(acc4[c4].w);
    *(u16x4*)&dst[c4*4] = o;
  }
}

// ---------------- Kernel 3: SW = (W @ rot^T) * s -> bf16, MFMA -------------
__global__ __launch_bounds__(256) void wtrans_kernel(
    const float* __restrict__ W, const u16* __restrict__ rotb,
    const float* __restrict__ sscale, u16* __restrict__ SW) {
  const int rt = blockIdx.x;            // row tile 0..31
  const int s  = blockIdx.y;            // superblock 0..31
  const int t  = threadIdx.x;
  __shared__ u16 Asw[128*128];          // W tile bf16, swizzled
  __shared__ u16 Bsw[128*128];          // rot_s bf16, swizzled
  // stage A: granule g: row=g>>5, gc=g&31 (f32x4). Coalesced 16B/lane.
  #pragma unroll
  for (int p = 0; p < 16; ++p) {
    const int g = p*256 + t;
    const int row = g >> 5, gc = g & 31;
    float4 v = *(const float4*)(W + (size_t)(rt*128 + row)*4096 + s*128 + gc*4);
    u16x4 o;
    o.x = f2bf(v.x); o.y = f2bf(v.y); o.z = f2bf(v.z); o.w = f2bf(v.w);
    const int chunk = (gc >> 1) ^ (row & 7);
    *(u16x4*)&Asw[row*128 + chunk*8 + (gc & 1)*4] = o;
  }
  // stage B: granule g: row=g>>4, ch=g&15 (u16x8). Coalesced 16B/lane.
  const u16* rsrc = rotb + (size_t)s*16384;
  #pragma unroll
  for (int p = 0; p < 8; ++p) {
    const int g = p*256 + t;
    const int row = g >> 4, ch = g & 15;
    u16x8 v = *(const u16x8*)(rsrc + row*128 + ch*8);
    *(u16x8*)&Bsw[row*128 + ((ch ^ (row & 7))*8)] = v;
  }
  __syncthreads();
  const int w = t >> 6, l = t & 63;
  const int fr = l & 15, fq = l >> 4;
  const int wm = (w >> 1)*64, wn = (w & 1)*64;
  f32x4 acc[4][4] = {};
  #pragma unroll
  for (int ks = 0; ks < 4; ++ks) {
    bf16x8 af[4], bfr[4];
    #pragma unroll
    for (int m = 0; m < 4; ++m)
      af[m] = *(const bf16x8*)&Asw[(wm + m*16 + fr)*128 + (((ks*4 + fq) ^ (fr & 7))*8)];
    #pragma unroll
    for (int n = 0; n < 4; ++n)
      bfr[n] = *(const bf16x8*)&Bsw[(wn + n*16 + fr)*128 + (((ks*4 + fq) ^ (fr & 7))*8)];
    #pragma unroll
    for (int m = 0; m < 4; ++m)
      #pragma unroll
      for (int n = 0; n < 4; ++n)
        acc[m][n] = __builtin_amdgcn_mfma_f32_16x16x32_bf16(
            af[m], bfr[n], acc[m][n], 0, 0, 0);
  }
  // epilogue: C/D col = fr (output col), row = fq*4 + reg; scale by boft_s
  #pragma unroll
  for (int m = 0; m < 4; ++m) {
    #pragma unroll
    for (int r = 0; r < 4; ++r) {
      const int row = rt*128 + wm + m*16 + fq*4 + r;
      const float sc = sscale[row];
      #pragma unroll
      for (int n = 0; n < 4; ++n) {
        const int col = s*128 + wn + n*16 + fr;
        SW[(size_t)row*4096 + col] = f2bf(acc[m][n][r] * sc);
      }
    }
  }
}

// ---------------- Kernel 4: x f32 -> bf16 ----------------------------------
__global__ __launch_bounds__(256) void cvt_kernel(
    const float* __restrict__ x, u16* __restrict__ xb) {
  const size_t i = (size_t)blockIdx.x * 256 + threadIdx.x;  // 8 elems/thread
  const float4* p = (const float4*)x + i*2;
  float4 a = p[0], b = p[1];
  u16x8 o;
  o[0] = f2bf(a.x); o[1] = f2bf(a.y); o[2] = f2bf(a.z); o[3] = f2bf(a.w);
  o[4] = f2bf(b.x); o[5] = f2bf(b.y); o[6] = f2bf(b.z); o[7] = f2bf(b.w);
  *(u16x8*)(xb + i*8) = o;
}

// ---------------- Kernel 5: bf16 MFMA GEMM — m201-faithful 8-phase ---------
// R12: exact m201 template port. 2 K-tiles/iter (t0=buf0, t1=buf1), 8 phases,
// each: {ds-reads for THIS phase's MFMA; 1 half-tile stage (2 gloads);
// [lgkmcnt(8) if 12 reads]; bar; lgkmcnt(0); setprio1; 16 MFMA; setprio0; bar}.
// Stage slots derived from WAR drains (B drained after P2/P6, A after P3/P7):
//   P1:t1.hA0 P2:t1.hA1 P3:c0.hB0 P4:c0.hB1 P5:c0.hA0 P6:c0.hA1
//   P7:c1.hB0 P8:c1.hB1   (c0=2it+2->buf0, c1=2it+3->buf1)
// vmcnt(4) at P4 (t1 landed; its loads issued >=2 phases prior) and P8
// (c0 landed). Never 0 mid-loop; it==31 -> vmcnt(0) at P4.
#define GLDS16(g, l)                                                   \
  __builtin_amdgcn_global_load_lds(                                    \
      (const __attribute__((address_space(1))) void*)(g),              \
      (__attribute__((address_space(3))) void*)(l), 16, 0, 0)

__device__ __forceinline__ void bar() {
  asm volatile("" ::: "memory");
  __builtin_amdgcn_s_barrier();
  asm volatile("" ::: "memory");
}

__global__ __launch_bounds__(512, 2) void gemm_kernel(
    const u16* __restrict__ A, const u16* __restrict__ B,
    const float* __restrict__ bias, float* __restrict__ C) {
  constexpr int K = 4096, N = 4096, NT = 64;   // K-tiles of BK=64
  __shared__ u16 As[2*256*64];                 // [buf][256 rows][64 cols]
  __shared__ u16 Bs[2*256*64];
  const int t = threadIdx.x;
  const int w = t >> 6, l = t & 63;
  const int wr = w >> 2, wc = w & 3;            // wave -> (2 x 4) grid
  const int fr = l & 15, fq = l >> 4;

  // XCD-aware swizzle (nwg=256, %8==0 -> simple bijective form)
  const int wg  = blockIdx.x;
  const int swz = (wg & 7) * 32 + (wg >> 3);
  const int m0  = (swz & 15) * 256, n0 = (swz >> 4) * 256;

  // staging: thread t fills LDS-linear granule (row = w*8 + (l>>3), c = l&7);
  // that slot must hold logical col (l&7) ^ (row&7)  [row&7 = (l>>3)&7].
  const int grow = w*8 + (l >> 3);                       // + o*64 + half*128
  const int gcol = ((l & 7) ^ ((l >> 3) & 7)) * 8;
  const u16* aS = A + (size_t)(m0 + grow) * K + gcol;
  const u16* bS = B + (size_t)(n0 + grow) * K + gcol;
  const int wLds = w * 512;                               // u16, wave-uniform

  // read: logical col = fq + 4*ks; stored col = (fq ^ (fr&7)) ^ 4*ks
  const int colbase = (fq ^ (fr & 7)) * 8;                // u16; ks flips ^32
  const u16* aRd = As + (wr*128 + fr)*64;
  const u16* bRd = Bs + (wc*64  + fr)*64;

  auto stgA = [&](int buf, int half, int o, int kt_) {
    GLDS16(aS + (size_t)(half*128 + o*64) * K + (size_t)kt_*64,
           As + buf*16384 + half*8192 + o*4096 + wLds);
  };
  auto stgB = [&](int buf, int half, int o, int kt_) {
    GLDS16(bS + (size_t)(half*128 + o*64) * K + (size_t)kt_*64,
           Bs + buf*16384 + half*8192 + o*4096 + wLds);
  };

  f32x4 acc[8][4] = {};
  bf16x8 aF[4][2], bF[4][2];

  auto rdA = [&](int buf, int mh) {
    const u16* aC = aRd + buf*16384;
    #pragma unroll
    for (int m = 0; m < 4; ++m) {
      aF[m][0] = *(const bf16x8*)(aC + (mh*4 + m)*1024 + colbase);
      aF[m][1] = *(const bf16x8*)(aC + (mh*4 + m)*1024 + (colbase ^ 32));
    }
  };
  auto rdB = [&](int buf, int nh) {
    const u16* bC = bRd + buf*16384;
    #pragma unroll
    for (int n = 0; n < 2; ++n) {
      bF[nh*2 + n][0] = *(const bf16x8*)(bC + (nh*2 + n)*1024 + colbase);
      bF[nh*2 + n][1] = *(const bf16x8*)(bC + (nh*2 + n)*1024 + (colbase ^ 32));
    }
  };
  auto mma = [&](int mh, int nh) {
    __builtin_amdgcn_s_setprio(1);
    #pragma unroll
    for (int m = 0; m < 4; ++m)
      #pragma unroll
      for (int n = 0; n < 2; ++n)
        #pragma unroll
        for (int ks = 0; ks < 2; ++ks)
          acc[mh*4 + m][nh*2 + n] = __builtin_amdgcn_mfma_f32_16x16x32_bf16(
              aF[m][ks], bF[nh*2 + n][ks], acc[mh*4 + m][nh*2 + n], 0, 0, 0);
    __builtin_amdgcn_s_setprio(0);
  };

  // prologue: t0 full (B,A) -> buf0, t1.hB -> buf1.  Queue: [t0 x8, t1.hB x4]
  stgB(0,0,0,0); stgB(0,0,1,0); stgB(0,1,0,0); stgB(0,1,1,0);
  stgA(0,0,0,0); stgA(0,0,1,0); stgA(0,1,0,0); stgA(0,1,1,0);
  stgB(1,0,0,1); stgB(1,0,1,1); stgB(1,1,0,1); stgB(1,1,1,1);
  asm volatile("s_waitcnt vmcnt(4)" ::: "memory");   // t0 landed; t1.hB in flight
  bar();

  for (int it = 0; it < 32; ++it) {
    const int t1 = 2*it + 1, c0 = 2*it + 2, c1 = 2*it + 3;
    const bool more = (it < 31);
    // ---- P1: rd t0.A0 + t0.B01 (12); stg t1.hA0 ----
    rdA(0, 0); rdB(0, 0);
    stgA(1,0,0,t1); stgA(1,0,1,t1);
    asm volatile("s_waitcnt lgkmcnt(8)" ::: "memory");
    bar();
    asm volatile("s_waitcnt lgkmcnt(0)" ::: "memory");
    mma(0, 0);
    bar();
    // ---- P2: rd t0.B23 (4); stg t1.hA1 ----
    rdB(0, 1);
    stgA(1,1,0,t1); stgA(1,1,1,t1);
    bar();
    asm volatile("s_waitcnt lgkmcnt(0)" ::: "memory");
    mma(0, 1);
    bar();
    // ---- P3: rd t0.A1 (8); stg c0.hB0 ----
    rdA(0, 1);
    if (more) { stgB(0,0,0,c0); stgB(0,0,1,c0); }
    bar();
    asm volatile("s_waitcnt lgkmcnt(0)" ::: "memory");
    mma(1, 1);
    bar();
    // ---- P4: stg c0.hB1; vmcnt(4) [t1 fully landed] ----
    if (more) { stgB(0,1,0,c0); stgB(0,1,1,c0); }
    if (more) asm volatile("s_waitcnt vmcnt(4)" ::: "memory");
    else      asm volatile("s_waitcnt vmcnt(0)" ::: "memory");
    bar();
    mma(1, 0);
    bar();
    // ---- P5: rd t1.A0 + t1.B01 (12); stg c0.hA0 ----
    rdA(1, 0); rdB(1, 0);
    if (more) { stgA(0,0,0,c0); stgA(0,0,1,c0); }
    asm volatile("s_waitcnt lgkmcnt(8)" ::: "memory");
    bar();
    asm volatile("s_waitcnt lgkmcnt(0)" ::: "memory");
    mma(0, 0);
    bar();
    // ---- P6: rd t1.B23 (4); stg c0.hA1 ----
    rdB(1, 1);
    if (more) { stgA(0,1,0,c0); stgA(0,1,1,c0); }
    bar();
    asm volatile("s_waitcnt lgkmcnt(0)" ::: "memory");
    mma(0, 1);
    bar();
    // ---- P7: rd t1.A1 (8); stg c1.hB0 ----
    rdA(1, 1);
    if (more) { stgB(1,0,0,c1); stgB(1,0,1,c1); }
    bar();
    asm volatile("s_waitcnt lgkmcnt(0)" ::: "memory");
    mma(1, 1);
    bar();
    // ---- P8: stg c1.hB1; vmcnt(4) [c0 fully landed] ----
    if (more) { stgB(1,1,0,c1); stgB(1,1,1,c1); }
    if (more) asm volatile("s_waitcnt vmcnt(4)" ::: "memory");
    bar();
    mma(1, 0);
    bar();
  }

  // epilogue: C/D layout col = lane&15 (fr), row = fq*4 + reg
  #pragma unroll
  for (int nf = 0; nf < 4; ++nf) {
    const int col = n0 + wc*64 + nf*16 + fr;
    const float bv = bias[col];
    #pragma unroll
    for (int mf = 0; mf < 8; ++mf) {
      const int rowb = m0 + wr*128 + mf*16 + fq*4;
      #pragma unroll
      for (int r = 0; r < 4; ++r)
        C[(size_t)(rowb + r)*N + col] = acc[mf][nf][r] + bv;
    }
  }
}

extern "C" void kernel_launch(void* const* d_in, const int* in_sizes, int n_in,
                              void* d_out, int out_size, void* d_ws, size_t ws_size,
                              hipStream_t stream) {
  const float* x      = (const float*)d_in[0];   // (2,2048,4096)
  const float* W      = (const float*)d_in[1];   // (4096,4096)
  const float* bias   = (const float*)d_in[2];   // (4096)
  const float* boft_R = (const float*)d_in[3];   // (2,64,64,64)
  const float* boft_s = (const float*)d_in[4];   // (4096,1)
  float* out = (float*)d_out;

  char* ws = (char*)d_ws;
  float* Q    = (float*)ws;                        //  2 MB (128*64*64 f32)
  u16*   rotb = (u16*)  (ws + ((size_t)2  << 20)); //  1 MB (32*128*128 bf16)
  u16*   xb   = (u16*)  (ws + ((size_t)4  << 20)); // 32 MB
  u16*   swb  = (u16*)  (ws + ((size_t)36 << 20)); // 32 MB

  cayley_kernel  <<<128, 256, 0, stream>>>(boft_R, Q);
  rotbuild_kernel<<<32, 256, 0, stream>>>(Q, rotb);
  wtrans_kernel  <<<dim3(32, 32), 256, 0, stream>>>(W, rotb, boft_s, swb);
  cvt_kernel     <<<(16777216/8)/256, 256, 0, stream>>>(x, xb);
  gemm_kernel    <<<256, 512, 0, stream>>>(xb, swb, bias, out);
}